// Round 7
// baseline (182.318 us; speedup 1.0000x reference)
//
#include <hip/hip_runtime.h>
#include <hip/hip_bf16.h>
#include <math.h>

#define NBINS 10
#define NVALS 21   // 0:bce, 1..10: C_k cumulative counts (C_0=n_valid), 11..20: S_k
#define THREADS 256
#define VEC 4      // float4s per thread per batch -> 16 elements

// x-space thresholds: logit(k/10), k=1..9 (sigmoid(x) >= k/10  <=>  x >= logit(k/10))
__device__ __constant__ const float LGT[9] = {
    -2.1972245773362196f, -1.3862943611198906f, -0.8472978603872034f,
    -0.4054651081081645f, 0.0f, 0.4054651081081645f,
    0.8472978603872034f, 1.3862943611198906f, 2.1972245773362196f};

// Per-element: counts on SALU (ballot+popc into SGPRs), sums via shared v_cmp.
__device__ __forceinline__ void proc1(float x, float t0, float& bce, float& s0,
                                      float* __restrict__ sk,
                                      unsigned* __restrict__ ck, unsigned& nv) {
  bool valid = !__builtin_isnan(x) && !__builtin_isnan(t0);
  unsigned long long mv = __ballot(valid);
  nv += (unsigned)__popcll(mv);                 // SALU

  float t = __builtin_amdgcn_fmed3f(t0, 0.f, 1.f);
  float e2 = __expf(-x);                        // exp(-x): v_mul + v_exp
  float L = 1.f + e2;
  float p = __builtin_amdgcn_rcpf(L);           // sigmoid(x)
  float dv = p - t;
  float dvm = valid ? dv : 0.f;
  s0 += dvm;                                    // S_0 (threshold p>=0)
  float lg = __log2f(L);                        // softplus(-x)/ln2 = -log2(p)
  const float LN2 = 0.6931471805599453f;
  float coef = __builtin_fmaf(79.f * LN2, t, LN2);   // (80t+1-t)*ln2
  float omtx = __builtin_fmaf(-t, x, x);             // (1-t)*x
  float b = __builtin_fmaf(coef, lg, omtx);
  bce += valid ? b : 0.f;

#pragma unroll
  for (int k = 0; k < 9; ++k) {
    bool ge = x >= LGT[k];                      // one v_cmp (false for NaN)
    unsigned long long mk = __ballot(ge);       // same cmp, sgpr mask
    ck[k] += (unsigned)__popcll(mk & mv);       // s_and + s_bcnt1 + s_add (SALU)
    sk[k] += ge ? dvm : 0.f;                    // v_cndmask + v_add
  }
}

__device__ __forceinline__ void proc16(const float4* __restrict__ bx,
                                       const float4* __restrict__ bt,
                                       float& bce, float& s0, float* sk,
                                       unsigned* ck, unsigned& nv) {
#pragma unroll
  for (int k = 0; k < VEC; ++k) {
    proc1(bx[k].x, bt[k].x, bce, s0, sk, ck, nv);
    proc1(bx[k].y, bt[k].y, bce, s0, sk, ck, nv);
    proc1(bx[k].z, bt[k].z, bce, s0, sk, ck, nv);
    proc1(bx[k].w, bt[k].w, bce, s0, sk, ck, nv);
  }
}

__device__ __forceinline__ void load_batch(const float4* __restrict__ p4,
                                           const float4* __restrict__ t4,
                                           long long i, float4* bx, float4* bt) {
#pragma unroll
  for (int k = 0; k < VEC; ++k) {
    bx[k] = p4[i + k * THREADS];   // each instr: 64 lanes x 16B contiguous
    bt[k] = t4[i + k * THREADS];
  }
}

__global__ __launch_bounds__(THREADS, 4) void dl_partial(
    const float* __restrict__ pred, const float* __restrict__ targ,
    long long n, float* __restrict__ ws, int grid) {
  __shared__ float red[4][NVALS];
  const int tid = threadIdx.x;
  const long long nvec = n >> 2;                       // float4 count
  const long long layer = (long long)grid * THREADS * VEC;
  const long long F = nvec / layer;                    // full layers
  const long long base = (long long)blockIdx.x * (THREADS * VEC) + tid;

  float bce = 0.f, s0 = 0.f;
  float sk[9];
  unsigned ck[9];
  unsigned nv = 0;
#pragma unroll
  for (int k = 0; k < 9; ++k) { sk[k] = 0.f; ck[k] = 0u; }

  const float4* p4 = (const float4*)pred;
  const float4* t4 = (const float4*)targ;

  // deep-pipelined main loop: 8 dwordx4 in flight across a 16-elem compute phase
  float4 ax[VEC], at[VEC], bx_[VEC], bt_[VEC];
  long long li = 0;
  if (F > 0) load_batch(p4, t4, base, ax, at);
  for (; li + 2 <= F; li += 2) {
    load_batch(p4, t4, base + (li + 1) * layer, bx_, bt_);
    proc16(ax, at, bce, s0, sk, ck, nv);
    if (li + 2 < F) load_batch(p4, t4, base + (li + 2) * layer, ax, at);
    proc16(bx_, bt_, bce, s0, sk, ck, nv);
  }
  if (li < F) proc16(ax, at, bce, s0, sk, ck, nv);

  // float4 tail beyond full layers (grid-stride, VEC=1)
  for (long long j = F * layer + (long long)blockIdx.x * THREADS + tid;
       j < nvec; j += (long long)grid * THREADS) {
    float4 xv = p4[j], tv = t4[j];
    proc1(xv.x, tv.x, bce, s0, sk, ck, nv);
    proc1(xv.y, tv.y, bce, s0, sk, ck, nv);
    proc1(xv.z, tv.z, bce, s0, sk, ck, nv);
    proc1(xv.w, tv.w, bce, s0, sk, ck, nv);
  }
  // scalar remainder (n % 4)
  long long ti = (nvec << 2) + (long long)blockIdx.x * THREADS + tid;
  if (ti < n) proc1(pred[ti], targ[ti], bce, s0, sk, ck, nv);

  // pack + wave reduce (uniform SALU counts contribute from lane0 only)
  float vals[NVALS];
  const int lane = tid & 63;
  vals[0] = bce;
  vals[1] = (lane == 0) ? (float)nv : 0.f;            // C_0 = n_valid
#pragma unroll
  for (int k = 0; k < 9; ++k) {
    vals[2 + k] = (lane == 0) ? (float)ck[k] : 0.f;   // C_1..C_9
    vals[12 + k] = sk[k];                             // S_1..S_9
  }
  vals[11] = s0;                                      // S_0
#pragma unroll
  for (int v = 0; v < NVALS; ++v) {
#pragma unroll
    for (int off = 32; off; off >>= 1) vals[v] += __shfl_xor(vals[v], off, 64);
  }
  const int wave = tid >> 6;
  if (lane == 0) {
#pragma unroll
    for (int v = 0; v < NVALS; ++v) red[wave][v] = vals[v];
  }
  __syncthreads();
  if (tid < NVALS) {
    float s = red[0][tid] + red[1][tid] + red[2][tid] + red[3][tid];
    ws[(long long)tid * grid + blockIdx.x] = s;
  }
}

__global__ __launch_bounds__(THREADS) void dl_final(
    const float* __restrict__ ws, float* __restrict__ out, int grid) {
  __shared__ double totals[NVALS];
  __shared__ double wred[4];
  const int tid = threadIdx.x;
  for (int r = 0; r < NVALS; ++r) {
    double psum = 0.0;
    for (int i = tid; i < grid; i += THREADS)
      psum += (double)ws[(long long)r * grid + i];
#pragma unroll
    for (int off = 32; off; off >>= 1) psum += __shfl_xor(psum, off, 64);
    if ((tid & 63) == 0) wred[tid >> 6] = psum;
    __syncthreads();
    if (tid == 0) totals[r] = wred[0] + wred[1] + wred[2] + wred[3];
    __syncthreads();
  }
  if (tid == 0) {
    double bce = totals[0];
    double nvd = totals[1];                   // C_0
    double dist = 0.0;
    for (int b = 0; b < NBINS; ++b) {
      double Cb = totals[1 + b];
      double Cb1 = (b < NBINS - 1) ? totals[2 + b] : 0.0;
      double Sb = totals[11 + b];
      double Sb1 = (b < NBINS - 1) ? totals[12 + b] : 0.0;
      double c = Cb - Cb1;                    // per-bin count (exact)
      double sd = Sb - Sb1;                   // per-bin sum (p-t)
      double safe = c > 1.0 ? c : 1.0;
      if (c > 10.0) dist += fabs(sd) / safe;
    }
    out[0] = (float)(bce / nvd + dist / (double)NBINS * 0.2);
  }
}

extern "C" void kernel_launch(void* const* d_in, const int* in_sizes, int n_in,
                              void* d_out, int out_size, void* d_ws, size_t ws_size,
                              hipStream_t stream) {
  const float* pred = (const float*)d_in[0];
  const float* targ = (const float*)d_in[1];
  const long long n = (long long)in_sizes[0];
  float* out = (float*)d_out;
  float* ws = (float*)d_ws;

  int grid = 2048;
  while (grid > 64 && (size_t)NVALS * grid * sizeof(float) > ws_size) grid >>= 1;

  dl_partial<<<grid, THREADS, 0, stream>>>(pred, targ, n, ws, grid);
  dl_final<<<1, THREADS, 0, stream>>>(ws, out, grid);
}

// Round 8
// 140.741 us; speedup vs baseline: 1.2954x; 1.2954x over previous
//
#include <hip/hip_runtime.h>
#include <hip/hip_bf16.h>
#include <math.h>

#define NBINS 10
#define NVALS 21          // 0:bce, 1..10:counts, 11..20:sum(p-t)
#define THREADS 256
#define HSTRIDE 11        // words/thread; gcd(11,32)=1 -> 2-way bases (free)

typedef float v4f __attribute__((ext_vector_type(4)));

__device__ __forceinline__ v4f ntload(const v4f* p) {
  return __builtin_nontemporal_load(p);   // global_load_dwordx4 ... nt
}

// Per-element: minimal-VALU scatter.
//  - sums: single b32 LDS RMW into private stride-11 slot
//  - counts: packed 6-bit fields in one u64 VGPR, flushed every 32 elems
__device__ __forceinline__ void proc(float x0, float t0, float& bce_acc,
                                     unsigned long long& c6,
                                     float* __restrict__ my) {
  bool valid = (x0 == x0) && (t0 == t0);
  float t = __builtin_amdgcn_fmed3f(t0, 0.f, 1.f);
  float e = __expf(-fabsf(x0));                 // exp(-|x|)
  float L = 1.f + e;
  float r = __builtin_amdgcn_rcpf(L);
  float p = (x0 >= 0.f) ? r : e * r;            // sigmoid(x); NaN-in -> NaN
  float l2p = __log2f(p);
  const float NLN2 = -0.6931471805599453f;
  float coef2 = __builtin_fmaf(79.f * NLN2, t, NLN2);  // -(80t+1-t)ln2
  float omtx = __builtin_fmaf(-t, x0, x0);             // (1-t)x
  float b = __builtin_fmaf(coef2, l2p, omtx);
  bce_acc += valid ? b : 0.f;

  int ib = (int)(p * 10.f);                     // NaN -> 0 (v_cvt), masked below
  ib = ib > 9 ? 9 : ib;
  float d = valid ? (p - t) : 0.f;
  my[ib] += d;                                  // ds_read_b32+add+ds_write_b32
  unsigned inc = valid ? 1u : 0u;
  c6 += (unsigned long long)inc << (unsigned)(ib * 6);
}

__device__ __forceinline__ void proc4(v4f xv, v4f tv, float& bce,
                                      unsigned long long& c6, float* my) {
  proc(xv[0], tv[0], bce, c6, my);
  proc(xv[1], tv[1], bce, c6, my);
  proc(xv[2], tv[2], bce, c6, my);
  proc(xv[3], tv[3], bce, c6, my);
}

__global__ __launch_bounds__(THREADS, 8) void dl_partial(
    const float* __restrict__ pred, const float* __restrict__ targ,
    long long n, float* __restrict__ ws, int grid) {
  __shared__ float hist[THREADS * HSTRIDE];   // 11264 B
  __shared__ float red[4][NVALS];             // + 336 B -> 8 blocks/CU

  const int tid = threadIdx.x;
  float* my = hist + tid * HSTRIDE;
#pragma unroll
  for (int b = 0; b < NBINS; ++b) my[b] = 0.f;

  const long long gid = (long long)blockIdx.x * THREADS + tid;
  const long long s = (long long)grid * THREADS;   // stride in float4 units
  const long long nvec = n >> 2;

  float bce = 0.f;
  unsigned long long c6 = 0ull;
  unsigned cnt[NBINS];
#pragma unroll
  for (int b = 0; b < NBINS; ++b) cnt[b] = 0u;

  const v4f* p4 = (const v4f*)pred;
  const v4f* t4 = (const v4f*)targ;

  // depth-2 ping-pong prefetch, nt loads
  long long i = gid;
  v4f XA{}, TA{}, XB{}, TB{};
  bool hA = i < nvec;
  if (hA) { XA = ntload(p4 + i); TA = ntload(t4 + i); }
  bool hB = (i + s) < nvec;
  if (hB) { XB = ntload(p4 + i + s); TB = ntload(t4 + i + s); }
  unsigned it = 0;
  while (hA) {
    // stage A: consume batch@i, prefetch batch@i+2s into its slot
    bool hp = (i + 2 * s) < nvec;
    {
      v4f px{}, pt{};
      if (hp) { px = ntload(p4 + i + 2 * s); pt = ntload(t4 + i + 2 * s); }
      proc4(XA, TA, bce, c6, my);
      XA = px; TA = pt;
    }
    // stage B: consume batch@i+s, prefetch batch@i+3s
    if (hB) {
      bool hq = (i + 3 * s) < nvec;
      v4f px{}, pt{};
      if (hq) { px = ntload(p4 + i + 3 * s); pt = ntload(t4 + i + 3 * s); }
      proc4(XB, TB, bce, c6, my);
      XB = px; TB = pt;
      hB = hq;
    }
    hA = hp;
    i += 2 * s;
    if ((++it & 3u) == 0u) {          // every 8 batches = 32 elems (< 63 cap)
#pragma unroll
      for (int b = 0; b < NBINS; ++b)
        cnt[b] += (unsigned)((c6 >> (6 * b)) & 63ull);
      c6 = 0ull;
    }
  }
  // scalar remainder (n % 4 < 4 elements total)
  long long ti = (nvec << 2) + gid;
  if (ti < n) proc(pred[ti], targ[ti], bce, c6, my);
#pragma unroll
  for (int b = 0; b < NBINS; ++b)
    cnt[b] += (unsigned)((c6 >> (6 * b)) & 63ull);

  // pack + wave reduce (own LDS slots: same-wave program order, no barrier)
  float vals[NVALS];
  vals[0] = bce;
#pragma unroll
  for (int b = 0; b < NBINS; ++b) {
    vals[1 + b] = (float)cnt[b];   // exact (<= 128/thread)
    vals[11 + b] = my[b];
  }
#pragma unroll
  for (int v = 0; v < NVALS; ++v) {
#pragma unroll
    for (int off = 32; off; off >>= 1) vals[v] += __shfl_xor(vals[v], off, 64);
  }
  const int lane = tid & 63;
  const int wave = tid >> 6;
  if (lane == 0) {
#pragma unroll
    for (int v = 0; v < NVALS; ++v) red[wave][v] = vals[v];
  }
  __syncthreads();
  if (tid < NVALS) {
    float sum = red[0][tid] + red[1][tid] + red[2][tid] + red[3][tid];
    ws[(long long)tid * grid + blockIdx.x] = sum;  // SoA, coalesced final pass
  }
}

__global__ __launch_bounds__(THREADS) void dl_final(
    const float* __restrict__ ws, float* __restrict__ out, int grid) {
  __shared__ double totals[NVALS];
  __shared__ double wred[4];
  const int tid = threadIdx.x;
  for (int r = 0; r < NVALS; ++r) {
    double psum = 0.0;
    for (int i = tid; i < grid; i += THREADS)
      psum += (double)ws[(long long)r * grid + i];
#pragma unroll
    for (int off = 32; off; off >>= 1) psum += __shfl_xor(psum, off, 64);
    if ((tid & 63) == 0) wred[tid >> 6] = psum;
    __syncthreads();
    if (tid == 0) totals[r] = wred[0] + wred[1] + wred[2] + wred[3];
    __syncthreads();
  }
  if (tid == 0) {
    double bce = totals[0];
    double nv = 0.0;
    for (int b = 0; b < NBINS; ++b) nv += totals[1 + b];  // n_valid = sum counts
    double dist = 0.0;
    for (int b = 0; b < NBINS; ++b) {
      double c = totals[1 + b], sd = totals[11 + b];
      double safe = c > 1.0 ? c : 1.0;
      if (c > 10.0) dist += fabs(sd) / safe;
    }
    out[0] = (float)(bce / nv + dist / (double)NBINS * 0.2);
  }
}

extern "C" void kernel_launch(void* const* d_in, const int* in_sizes, int n_in,
                              void* d_out, int out_size, void* d_ws, size_t ws_size,
                              hipStream_t stream) {
  const float* pred = (const float*)d_in[0];
  const float* targ = (const float*)d_in[1];
  const long long n = (long long)in_sizes[0];
  float* out = (float*)d_out;
  float* ws = (float*)d_ws;

  int grid = 2048;  // 8 blocks/CU x 256 CUs; 16.8M float4 / 524288 = 32 iters/thread
  while (grid > 64 && (size_t)NVALS * grid * sizeof(float) > ws_size) grid >>= 1;

  dl_partial<<<grid, THREADS, 0, stream>>>(pred, targ, n, ws, grid);
  dl_final<<<1, THREADS, 0, stream>>>(ws, out, grid);
}